// Round 10
// baseline (432.996 us; speedup 1.0000x reference)
//
#include <hip/hip_runtime.h>

#define N_NODES 50000
#define NEDGE   800000
#define D       128
#define EPS     1e-5f
#define NT      3125                    // N_NODES/16 row-subtiles (exact)
#define NUNITS  800000                  // NT*4*64 16B-units per plane
#define NHALF   ((size_t)N_NODES * 64)
#define FILL_T  200192                  // 782*256 threads in k_fill

typedef __attribute__((ext_vector_type(8))) short bf16x8;
typedef __attribute__((ext_vector_type(4))) float f32x4;
typedef __attribute__((ext_vector_type(8))) unsigned short u16x8;

// fp32 -> bf16 (RNE) as ushort bits
__device__ inline uint32_t bfhi(float f) {
    uint32_t u = __float_as_uint(f);
    u += 0x7fffu + ((u >> 16) & 1u);
    return u >> 16;
}
__device__ inline float bff(uint32_t h) { return __uint_as_float(h << 16); }

// ---------------- exclusive scan (3 kernels) ----------------
__global__ __launch_bounds__(256) void k_scan1(const int* __restrict__ degi,
                                               int* __restrict__ offs,
                                               int* __restrict__ bsum) {
    __shared__ int s[256];
    int tid = threadIdx.x;
    int i = blockIdx.x * 256 + tid;
    int v = (i < N_NODES) ? degi[i] : 0;
    s[tid] = v;
    __syncthreads();
    for (int d = 1; d < 256; d <<= 1) {
        int t = (tid >= d) ? s[tid - d] : 0;
        __syncthreads();
        s[tid] += t;
        __syncthreads();
    }
    if (i < N_NODES) offs[i] = s[tid] - v;   // exclusive
    if (tid == 255) bsum[blockIdx.x] = s[255];
}

__global__ __launch_bounds__(256) void k_scan2(int* __restrict__ bsum, int nb) {
    __shared__ int s[256];
    int tid = threadIdx.x;
    int v = (tid < nb) ? bsum[tid] : 0;
    s[tid] = v;
    __syncthreads();
    for (int d = 1; d < 256; d <<= 1) {
        int t = (tid >= d) ? s[tid - d] : 0;
        __syncthreads();
        s[tid] += t;
        __syncthreads();
    }
    if (tid < nb) bsum[tid] = s[tid] - v;    // exclusive block offsets
}

__global__ __launch_bounds__(256) void k_scan3(const int* __restrict__ degi,
                                               const int* __restrict__ bsum,
                                               int* __restrict__ offs,
                                               int* __restrict__ cursor,
                                               float* __restrict__ invdeg) {
    int i = blockIdx.x * 256 + threadIdx.x;
    if (i < N_NODES) {
        int o = offs[i] + bsum[blockIdx.x];
        offs[i] = o;
        cursor[i] = o;
        int dg = degi[i];
        invdeg[i] = 1.0f / (float)(dg > 0 ? dg : 1);
    }
    if (i == 0 && blockIdx.x == 0) offs[N_NODES] = NEDGE;
}

// ---------------- CSR bucket fill: 4 edges/thread for atomic ILP ----------------
__global__ __launch_bounds__(256) void k_fill(const int* __restrict__ src,
                                              const int* __restrict__ dst,
                                              int* __restrict__ cursor,
                                              int* __restrict__ csr) {
    int gid = blockIdx.x * 256 + threadIdx.x;
#pragma unroll
    for (int it = 0; it < 4; ++it) {
        int e = gid + it * FILL_T;
        if (e < NEDGE) {
            int p = atomicAdd(&cursor[dst[e]], 1);
            csr[p] = src[e];
        }
    }
}

// ---------------- x -> fragment planes + half-split hi plane; fused deg count ---
// Fragment unit (t,kc,l) = rows 16t+(l&15), cols 32kc+8*(l>>4)..+8.
// NEDGE == NUNITS: thread `flat` also counts edge `flat`'s dst (atomic latency
// hides under the streaming traffic).
__global__ __launch_bounds__(256) void k_tobf16(const float* __restrict__ X,
                                                unsigned short* __restrict__ PH,
                                                unsigned short* __restrict__ PL,
                                                unsigned short* __restrict__ XG,
                                                const int* __restrict__ dst,
                                                int* __restrict__ degi) {
    int flat = blockIdx.x * 256 + threadIdx.x;
    if (flat >= NUNITS) return;
    atomicAdd(&degi[dst[flat]], 1);
    int tb = flat >> 8;
    int kc = (flat >> 6) & 3;
    int l = flat & 63;
    int row = tb * 16 + (l & 15);
    int col = kc * 32 + (l >> 4) * 8;
    const float* p = X + (size_t)row * D + col;
    float4 a = *reinterpret_cast<const float4*>(p);
    float4 b = *reinterpret_cast<const float4*>(p + 4);
    float f[8] = {a.x, a.y, a.z, a.w, b.x, b.y, b.z, b.w};
    u16x8 oh, ol;
#pragma unroll
    for (int i = 0; i < 8; ++i) {
        uint32_t h = bfhi(f[i]);
        oh[i] = (unsigned short)h;
        ol[i] = (unsigned short)bfhi(f[i] - bff(h));
    }
    *reinterpret_cast<u16x8*>(PH + (size_t)flat * 8) = oh;
    *reinterpret_cast<u16x8*>(PL + (size_t)flat * 8) = ol;
    *reinterpret_cast<u16x8*>(XG + (size_t)(col >> 6) * NHALF + (size_t)row * 64 + (col & 63)) = oh;
}

// ---------------- BN+ReLU (bnfin fused): hbuf fp32 -> fragment + half planes ----
__global__ __launch_bounds__(256) void k_act(const float* __restrict__ H,
                                             const float* __restrict__ sums,
                                             const float* __restrict__ gamma,
                                             const float* __restrict__ beta,
                                             unsigned short* __restrict__ PH,
                                             unsigned short* __restrict__ PL,
                                             unsigned short* __restrict__ XG) {
    int flat = blockIdx.x * 256 + threadIdx.x;
    if (flat >= NUNITS) return;
    int tb = flat >> 8;
    int kc = (flat >> 6) & 3;
    int l = flat & 63;
    int row = tb * 16 + (l & 15);
    int col = kc * 32 + (l >> 4) * 8;
    const float invN = 1.0f / (float)N_NODES;
    const float* p = H + (size_t)row * D + col;
    float4 a = *reinterpret_cast<const float4*>(p);
    float4 b = *reinterpret_cast<const float4*>(p + 4);
    float hv[8] = {a.x, a.y, a.z, a.w, b.x, b.y, b.z, b.w};
    float4 s0 = *reinterpret_cast<const float4*>(sums + col);
    float4 s1 = *reinterpret_cast<const float4*>(sums + col + 4);
    float4 q0 = *reinterpret_cast<const float4*>(sums + 128 + col);
    float4 q1 = *reinterpret_cast<const float4*>(sums + 128 + col + 4);
    float4 g0 = *reinterpret_cast<const float4*>(gamma + col);
    float4 g1 = *reinterpret_cast<const float4*>(gamma + col + 4);
    float4 e0 = *reinterpret_cast<const float4*>(beta + col);
    float4 e1 = *reinterpret_cast<const float4*>(beta + col + 4);
    float sm[8] = {s0.x, s0.y, s0.z, s0.w, s1.x, s1.y, s1.z, s1.w};
    float sq[8] = {q0.x, q0.y, q0.z, q0.w, q1.x, q1.y, q1.z, q1.w};
    float gm[8] = {g0.x, g0.y, g0.z, g0.w, g1.x, g1.y, g1.z, g1.w};
    float bt[8] = {e0.x, e0.y, e0.z, e0.w, e1.x, e1.y, e1.z, e1.w};
    u16x8 oh, ol;
#pragma unroll
    for (int i = 0; i < 8; ++i) {
        float mu = sm[i] * invN;
        float var = sq[i] * invN - mu * mu;
        float sc = gm[i] * rsqrtf(var + EPS);
        float sh = bt[i] - mu * sc;
        float f = fmaxf(hv[i] * sc + sh, 0.f);
        uint32_t h = bfhi(f);
        oh[i] = (unsigned short)h;
        ol[i] = (unsigned short)bfhi(f - bff(h));
    }
    *reinterpret_cast<u16x8*>(PH + (size_t)flat * 8) = oh;
    *reinterpret_cast<u16x8*>(PL + (size_t)flat * 8) = ol;
    *reinterpret_cast<u16x8*>(XG + (size_t)(col >> 6) * NHALF + (size_t)row * 64 + (col & 63)) = oh;
}

// ---------------- mean aggregation: gather half-plane, write hn fragment planes -
// XCD-sharded by bit2 of bid. 32 nodes/block, 8 lanes/node (128B rows).
__global__ __launch_bounds__(256) void k_agg(const unsigned short* __restrict__ XG,
                                             const int* __restrict__ offs,
                                             const int* __restrict__ csr,
                                             const float* __restrict__ invdeg,
                                             unsigned short* __restrict__ HNH,
                                             unsigned short* __restrict__ HNL) {
    int bid = blockIdx.x;
    int half = (bid >> 2) & 1;
    int nb = (bid >> 3) * 4 + (bid & 3);
    if (nb >= 1563) return;
    int n = nb * 32 + (threadIdx.x >> 3);
    if (n >= N_NODES) return;
    int c = (threadIdx.x & 7) * 8;        // col within half
    const unsigned short* XP = XG + (size_t)half * NHALF;

    int e0 = offs[n], e1 = offs[n + 1];
    float a0[8], a1[8];
#pragma unroll
    for (int i = 0; i < 8; ++i) { a0[i] = 0.f; a1[i] = 0.f; }

    int e = e0;
    for (; e + 2 <= e1; e += 2) {
        int s0i = csr[e], s1i = csr[e + 1];
        u16x8 v0 = *reinterpret_cast<const u16x8*>(XP + (size_t)s0i * 64 + c);
        u16x8 v1 = *reinterpret_cast<const u16x8*>(XP + (size_t)s1i * 64 + c);
#pragma unroll
        for (int i = 0; i < 8; ++i) {
            a0[i] += bff((unsigned short)v0[i]);
            a1[i] += bff((unsigned short)v1[i]);
        }
    }
    if (e < e1) {
        int s0i = csr[e];
        u16x8 v0 = *reinterpret_cast<const u16x8*>(XP + (size_t)s0i * 64 + c);
#pragma unroll
        for (int i = 0; i < 8; ++i)
            a0[i] += bff((unsigned short)v0[i]);
    }
    float id = invdeg[n];
    u16x8 oh, ol;
#pragma unroll
    for (int i = 0; i < 8; ++i) {
        float m = (a0[i] + a1[i]) * id;
        uint32_t h = bfhi(m);
        oh[i] = (unsigned short)h;
        ol[i] = (unsigned short)bfhi(m - bff(h));
    }
    int gc = half * 64 + c;
    int kc = gc >> 5;
    int l = (n & 15) + ((gc >> 3) & 3) * 16;
    size_t unit = ((size_t)(n >> 4) * 4 + kc) * 64 + l;
    *reinterpret_cast<u16x8*>(HNH + unit * 8) = oh;
    *reinterpret_cast<u16x8*>(HNL + unit * 8) = ol;
}

// -------- weight prep (transpose + hi/lo split) + zero degi/sums buffers --------
__global__ __launch_bounds__(256) void k_wprep(const float* __restrict__ W0,
                                               const float* __restrict__ W1,
                                               const float* __restrict__ W2,
                                               const float* __restrict__ W3,
                                               const float* __restrict__ W4,
                                               const float* __restrict__ W5,
                                               unsigned short* __restrict__ wt,
                                               int* __restrict__ degi,
                                               float* __restrict__ sums1,
                                               float* __restrict__ sums2) {
    int gid = blockIdx.x * 256 + threadIdx.x;     // 0..98303
    if (gid < N_NODES) degi[gid] = 0;
    if (gid < 256) { sums1[gid] = 0.f; sums2[gid] = 0.f; }
    int mat = blockIdx.x >> 6;
    const float* srcs[6] = {W0, W1, W2, W3, W4, W5};
    const float* W = srcs[mat];
    int t = (blockIdx.x & 63) * 256 + threadIdx.x;
    int k = t >> 7;
    int n = t & 127;
    float w = W[k * 128 + n];
    uint32_t h = bfhi(w);
    uint32_t l = bfhi(w - bff(h));
    unsigned short* base = wt + (size_t)mat * 32768;
    base[n * 128 + k] = (unsigned short)h;
    base[16384 + n * 128 + k] = (unsigned short)l;
}

// ---------------- MFMA GEMM: fragment-ordered planes, fully coalesced -----------
__global__ __launch_bounds__(256, 4) void k_mm(const unsigned short* __restrict__ PH,
                                               const unsigned short* __restrict__ PL,
                                               const unsigned short* __restrict__ HNH,
                                               const unsigned short* __restrict__ HNL,
                                               const unsigned short* __restrict__ WsT,
                                               const unsigned short* __restrict__ WnT,
                                               const float* __restrict__ bias,
                                               float* __restrict__ OUT,
                                               int doStats,
                                               float* __restrict__ sums) {
    const int tid = threadIdx.x;
    const int lane = tid & 63;
    const int wave = tid >> 6;
    const int mlo = lane & 15;
    const int g = lane >> 4;
    const int ch = blockIdx.x & 1;
    const int t0 = (blockIdx.x >> 1) * 4;
    const int row0 = t0 * 16;
    const int col = ch * 64 + wave * 16 + mlo;
    const float bcol = bias[col];

    f32x4 acc[4];
#pragma unroll
    for (int s = 0; s < 4; ++s) acc[s] = (f32x4){0.f, 0.f, 0.f, 0.f};

#pragma unroll
    for (int kc = 0; kc < 4; ++kc) {
        int ko = kc * 32 + g * 8;
        bf16x8 wsh = *reinterpret_cast<const bf16x8*>(WsT + (size_t)col * 128 + ko);
        bf16x8 wsl = *reinterpret_cast<const bf16x8*>(WsT + 16384 + (size_t)col * 128 + ko);
        bf16x8 wnh = *reinterpret_cast<const bf16x8*>(WnT + (size_t)col * 128 + ko);
        bf16x8 wnl = *reinterpret_cast<const bf16x8*>(WnT + 16384 + (size_t)col * 128 + ko);
#pragma unroll
        for (int s = 0; s < 4; ++s) {
            int t = t0 + s;
            u16x8 xh, xl, ah, al;
            if (t < NT) {
                size_t idx = (((size_t)t * 4 + kc) * 64 + lane) * 8;
                xh = *reinterpret_cast<const u16x8*>(PH + idx);
                xl = *reinterpret_cast<const u16x8*>(PL + idx);
                ah = *reinterpret_cast<const u16x8*>(HNH + idx);
                al = *reinterpret_cast<const u16x8*>(HNL + idx);
            } else {
                u16x8 z = {0, 0, 0, 0, 0, 0, 0, 0};
                xh = z; xl = z; ah = z; al = z;
            }
            bf16x8 bxh = *(bf16x8*)&xh, bxl = *(bf16x8*)&xl;
            bf16x8 bah = *(bf16x8*)&ah, bal = *(bf16x8*)&al;
            acc[s] = __builtin_amdgcn_mfma_f32_16x16x32_bf16(bxh, wsh, acc[s], 0, 0, 0);
            acc[s] = __builtin_amdgcn_mfma_f32_16x16x32_bf16(bxh, wsl, acc[s], 0, 0, 0);
            acc[s] = __builtin_amdgcn_mfma_f32_16x16x32_bf16(bxl, wsh, acc[s], 0, 0, 0);
            acc[s] = __builtin_amdgcn_mfma_f32_16x16x32_bf16(bah, wnh, acc[s], 0, 0, 0);
            acc[s] = __builtin_amdgcn_mfma_f32_16x16x32_bf16(bah, wnl, acc[s], 0, 0, 0);
            acc[s] = __builtin_amdgcn_mfma_f32_16x16x32_bf16(bal, wnh, acc[s], 0, 0, 0);
        }
    }

    // ---- epilogue: bias, store fp32, fused BN stats ----
    float cs = 0.f, cq = 0.f;
#pragma unroll
    for (int s = 0; s < 4; ++s) {
#pragma unroll
        for (int r = 0; r < 4; ++r) {
            int grow = row0 + s * 16 + g * 4 + r;
            if (grow < N_NODES) {
                float v = acc[s][r] + bcol;
                OUT[(size_t)grow * D + col] = v;
                cs += v; cq += v * v;
            }
        }
    }
    if (doStats) {
        cs += __shfl_xor(cs, 16); cs += __shfl_xor(cs, 32);
        cq += __shfl_xor(cq, 16); cq += __shfl_xor(cq, 32);
        if (lane < 16) {
            atomicAdd(&sums[col], cs);
            atomicAdd(&sums[128 + col], cq);
        }
    }
}

// ---------------- launch ----------------
extern "C" void kernel_launch(void* const* d_in, const int* in_sizes, int n_in,
                              void* d_out, int out_size, void* d_ws, size_t ws_size,
                              hipStream_t stream) {
    const float* x   = (const float*)d_in[0];
    const int*   src = (const int*)d_in[1];
    const int*   dst = (const int*)d_in[2];
    const float* Ws1 = (const float*)d_in[3];
    const float* Wn1 = (const float*)d_in[4];
    const float* b1  = (const float*)d_in[5];
    const float* g1  = (const float*)d_in[6];
    const float* be1 = (const float*)d_in[7];
    const float* Ws2 = (const float*)d_in[8];
    const float* Wn2 = (const float*)d_in[9];
    const float* b2  = (const float*)d_in[10];
    const float* g2  = (const float*)d_in[11];
    const float* be2 = (const float*)d_in[12];
    const float* Ws3 = (const float*)d_in[13];
    const float* Wn3 = (const float*)d_in[14];
    const float* b3  = (const float*)d_in[15];
    float* out = (float*)d_out;

    char* p = (char*)d_ws;
    auto alloc = [&](size_t bytes) -> char* {
        char* r = p;
        p += (bytes + 255) & ~(size_t)255;
        return r;
    };
    unsigned short* pfh = (unsigned short*)alloc((size_t)NUNITS * 16);  // fragment hi
    unsigned short* pfl = (unsigned short*)alloc((size_t)NUNITS * 16);  // fragment lo
    unsigned short* xg  = (unsigned short*)alloc((size_t)N_NODES * D * 2); // half-split hi
    unsigned short* hnh = (unsigned short*)alloc((size_t)NUNITS * 16);
    unsigned short* hnl = (unsigned short*)alloc((size_t)NUNITS * 16);
    float* hbuf   = (float*)alloc((size_t)N_NODES * D * 4);
    int*   csr    = (int*)alloc((size_t)NEDGE * 4);
    int*   offs   = (int*)alloc((size_t)(N_NODES + 1) * 4);
    int*   cursor = (int*)alloc((size_t)N_NODES * 4);
    int*   degi   = (int*)alloc((size_t)N_NODES * 4);
    float* invdeg = (float*)alloc((size_t)N_NODES * 4);
    int*   bsum   = (int*)alloc(1024);
    float* sums1  = (float*)alloc(256 * 4);
    float* sums2  = (float*)alloc(256 * 4);
    unsigned short* wt = (unsigned short*)alloc((size_t)6 * 32768 * 2);

    const int NB_N = (N_NODES + 255) / 256;        // 196
    const int NB_A = 3128;                         // 2 halves x 1563 node-blocks
    const int NB_M = 2 * ((N_NODES + 63) / 64);    // 1564
    const int NB_T = (NUNITS + 255) / 256;         // 3125
    const int NB_F = 782;

    const unsigned short* WsT1 = wt + 0 * 32768;
    const unsigned short* WnT1 = wt + 1 * 32768;
    const unsigned short* WsT2 = wt + 2 * 32768;
    const unsigned short* WnT2 = wt + 3 * 32768;
    const unsigned short* WsT3 = wt + 4 * 32768;
    const unsigned short* WnT3 = wt + 5 * 32768;

    // ---- prep: weights + zero degi/sums, x->planes + deg count, scan, fill ----
    k_wprep<<<384, 256, 0, stream>>>(Ws1, Wn1, Ws2, Wn2, Ws3, Wn3, wt, degi, sums1, sums2);
    k_tobf16<<<NB_T, 256, 0, stream>>>(x, pfh, pfl, xg, dst, degi);
    k_scan1<<<NB_N, 256, 0, stream>>>(degi, offs, bsum);
    k_scan2<<<1, 256, 0, stream>>>(bsum, NB_N);
    k_scan3<<<NB_N, 256, 0, stream>>>(degi, bsum, offs, cursor, invdeg);
    k_fill<<<NB_F, 256, 0, stream>>>(src, dst, cursor, csr);

    // ---- Layer 1 ----
    k_agg<<<NB_A, 256, 0, stream>>>(xg, offs, csr, invdeg, hnh, hnl);
    k_mm<<<NB_M, 256, 0, stream>>>(pfh, pfl, hnh, hnl, WsT1, WnT1, b1, hbuf, 1, sums1);
    k_act<<<NB_T, 256, 0, stream>>>(hbuf, sums1, g1, be1, pfh, pfl, xg);

    // ---- Layer 2 ----
    k_agg<<<NB_A, 256, 0, stream>>>(xg, offs, csr, invdeg, hnh, hnl);
    k_mm<<<NB_M, 256, 0, stream>>>(pfh, pfl, hnh, hnl, WsT2, WnT2, b2, hbuf, 1, sums2);
    k_act<<<NB_T, 256, 0, stream>>>(hbuf, sums2, g2, be2, pfh, pfl, xg);

    // ---- Layer 3 (fp32 out, no stats) ----
    k_agg<<<NB_A, 256, 0, stream>>>(xg, offs, csr, invdeg, hnh, hnl);
    k_mm<<<NB_M, 256, 0, stream>>>(pfh, pfl, hnh, hnl, WsT3, WnT3, b3, out, 0, sums1);
}

// Round 11
// 393.139 us; speedup vs baseline: 1.1014x; 1.1014x over previous
//
#include <hip/hip_runtime.h>

#define N_NODES 50000
#define NEDGE   800000
#define D       128
#define EPS     1e-5f
#define NT      3125                    // N_NODES/16 row-subtiles (exact)
#define NUNITS  800000                  // NT*4*64 16B-units per plane
#define NHALF   ((size_t)N_NODES * 64)
#define NPG     6250                    // nodes per XCD group (50000/8)

typedef __attribute__((ext_vector_type(8))) short bf16x8;
typedef __attribute__((ext_vector_type(4))) float f32x4;
typedef __attribute__((ext_vector_type(8))) unsigned short u16x8;

// fp32 -> bf16 (RNE) as ushort bits
__device__ inline uint32_t bfhi(float f) {
    uint32_t u = __float_as_uint(f);
    u += 0x7fffu + ((u >> 16) & 1u);
    return u >> 16;
}
__device__ inline float bff(uint32_t h) { return __uint_as_float(h << 16); }

// ---------------- exclusive scan (3 kernels) ----------------
__global__ __launch_bounds__(256) void k_scan1(const int* __restrict__ degi,
                                               int* __restrict__ offs,
                                               int* __restrict__ bsum) {
    __shared__ int s[256];
    int tid = threadIdx.x;
    int i = blockIdx.x * 256 + tid;
    int v = (i < N_NODES) ? degi[i] : 0;
    s[tid] = v;
    __syncthreads();
    for (int d = 1; d < 256; d <<= 1) {
        int t = (tid >= d) ? s[tid - d] : 0;
        __syncthreads();
        s[tid] += t;
        __syncthreads();
    }
    if (i < N_NODES) offs[i] = s[tid] - v;   // exclusive
    if (tid == 255) bsum[blockIdx.x] = s[255];
}

__global__ __launch_bounds__(256) void k_scan2(int* __restrict__ bsum, int nb) {
    __shared__ int s[256];
    int tid = threadIdx.x;
    int v = (tid < nb) ? bsum[tid] : 0;
    s[tid] = v;
    __syncthreads();
    for (int d = 1; d < 256; d <<= 1) {
        int t = (tid >= d) ? s[tid - d] : 0;
        __syncthreads();
        s[tid] += t;
        __syncthreads();
    }
    if (tid < nb) bsum[tid] = s[tid] - v;    // exclusive block offsets
}

__global__ __launch_bounds__(256) void k_scan3(const int* __restrict__ degi,
                                               const int* __restrict__ bsum,
                                               int* __restrict__ offs,
                                               int* __restrict__ cursor,
                                               float* __restrict__ invdeg) {
    int i = blockIdx.x * 256 + threadIdx.x;
    if (i < N_NODES) {
        int o = offs[i] + bsum[blockIdx.x];
        offs[i] = o;
        cursor[i] = o;
        int dg = degi[i];
        invdeg[i] = 1.0f / (float)(dg > 0 ? dg : 1);
    }
    if (i == 0 && blockIdx.x == 0) offs[N_NODES] = NEDGE;
}

// -------- CSR fill, XCD-sharded by dst range ----------------------------------
// Group g = bid&7 (round-robin bid->XCD pins group g to XCD g) scans all edges,
// processes only dst in [g*NPG,(g+1)*NPG): each XCD writes a private contiguous
// csr region -> no cross-XCD partial-line evictions. Correct for any mapping.
__global__ __launch_bounds__(256) void k_fill(const int* __restrict__ src,
                                              const int* __restrict__ dst,
                                              int* __restrict__ cursor,
                                              int* __restrict__ csr) {
    int grp = blockIdx.x & 7;
    int e = (blockIdx.x >> 3) * 256 + threadIdx.x;
    if (e >= NEDGE) return;
    int d = dst[e];
    int lo = grp * NPG;
    if (d >= lo && d < lo + NPG) {
        int p = atomicAdd(&cursor[d], 1);
        csr[p] = src[e];
    }
}

// ---------------- x -> fragment planes + half-split hi plane; fused deg count ---
__global__ __launch_bounds__(256) void k_tobf16(const float* __restrict__ X,
                                                unsigned short* __restrict__ PH,
                                                unsigned short* __restrict__ PL,
                                                unsigned short* __restrict__ XG,
                                                const int* __restrict__ dst,
                                                int* __restrict__ degi) {
    int flat = blockIdx.x * 256 + threadIdx.x;
    if (flat >= NUNITS) return;
    atomicAdd(&degi[dst[flat]], 1);
    int tb = flat >> 8;
    int kc = (flat >> 6) & 3;
    int l = flat & 63;
    int row = tb * 16 + (l & 15);
    int col = kc * 32 + (l >> 4) * 8;
    const float* p = X + (size_t)row * D + col;
    float4 a = *reinterpret_cast<const float4*>(p);
    float4 b = *reinterpret_cast<const float4*>(p + 4);
    float f[8] = {a.x, a.y, a.z, a.w, b.x, b.y, b.z, b.w};
    u16x8 oh, ol;
#pragma unroll
    for (int i = 0; i < 8; ++i) {
        uint32_t h = bfhi(f[i]);
        oh[i] = (unsigned short)h;
        ol[i] = (unsigned short)bfhi(f[i] - bff(h));
    }
    *reinterpret_cast<u16x8*>(PH + (size_t)flat * 8) = oh;
    *reinterpret_cast<u16x8*>(PL + (size_t)flat * 8) = ol;
    *reinterpret_cast<u16x8*>(XG + (size_t)(col >> 6) * NHALF + (size_t)row * 64 + (col & 63)) = oh;
}

// ---------------- BN+ReLU (bnfin fused): hbuf fp32 -> fragment + half planes ----
__global__ __launch_bounds__(256) void k_act(const float* __restrict__ H,
                                             const float* __restrict__ sums,
                                             const float* __restrict__ gamma,
                                             const float* __restrict__ beta,
                                             unsigned short* __restrict__ PH,
                                             unsigned short* __restrict__ PL,
                                             unsigned short* __restrict__ XG) {
    int flat = blockIdx.x * 256 + threadIdx.x;
    if (flat >= NUNITS) return;
    int tb = flat >> 8;
    int kc = (flat >> 6) & 3;
    int l = flat & 63;
    int row = tb * 16 + (l & 15);
    int col = kc * 32 + (l >> 4) * 8;
    const float invN = 1.0f / (float)N_NODES;
    const float* p = H + (size_t)row * D + col;
    float4 a = *reinterpret_cast<const float4*>(p);
    float4 b = *reinterpret_cast<const float4*>(p + 4);
    float hv[8] = {a.x, a.y, a.z, a.w, b.x, b.y, b.z, b.w};
    float4 s0 = *reinterpret_cast<const float4*>(sums + col);
    float4 s1 = *reinterpret_cast<const float4*>(sums + col + 4);
    float4 q0 = *reinterpret_cast<const float4*>(sums + 128 + col);
    float4 q1 = *reinterpret_cast<const float4*>(sums + 128 + col + 4);
    float4 g0 = *reinterpret_cast<const float4*>(gamma + col);
    float4 g1 = *reinterpret_cast<const float4*>(gamma + col + 4);
    float4 e0 = *reinterpret_cast<const float4*>(beta + col);
    float4 e1 = *reinterpret_cast<const float4*>(beta + col + 4);
    float sm[8] = {s0.x, s0.y, s0.z, s0.w, s1.x, s1.y, s1.z, s1.w};
    float sq[8] = {q0.x, q0.y, q0.z, q0.w, q1.x, q1.y, q1.z, q1.w};
    float gm[8] = {g0.x, g0.y, g0.z, g0.w, g1.x, g1.y, g1.z, g1.w};
    float bt[8] = {e0.x, e0.y, e0.z, e0.w, e1.x, e1.y, e1.z, e1.w};
    u16x8 oh, ol;
#pragma unroll
    for (int i = 0; i < 8; ++i) {
        float mu = sm[i] * invN;
        float var = sq[i] * invN - mu * mu;
        float sc = gm[i] * rsqrtf(var + EPS);
        float sh = bt[i] - mu * sc;
        float f = fmaxf(hv[i] * sc + sh, 0.f);
        uint32_t h = bfhi(f);
        oh[i] = (unsigned short)h;
        ol[i] = (unsigned short)bfhi(f - bff(h));
    }
    *reinterpret_cast<u16x8*>(PH + (size_t)flat * 8) = oh;
    *reinterpret_cast<u16x8*>(PL + (size_t)flat * 8) = ol;
    *reinterpret_cast<u16x8*>(XG + (size_t)(col >> 6) * NHALF + (size_t)row * 64 + (col & 63)) = oh;
}

// ---------------- mean aggregation: gather half-plane, 4-edge unroll ------------
// XCD-sharded by bit2 of bid. 32 nodes/block, 8 lanes/node (128B rows).
__global__ __launch_bounds__(256) void k_agg(const unsigned short* __restrict__ XG,
                                             const int* __restrict__ offs,
                                             const int* __restrict__ csr,
                                             const float* __restrict__ invdeg,
                                             unsigned short* __restrict__ HNH,
                                             unsigned short* __restrict__ HNL) {
    int bid = blockIdx.x;
    int half = (bid >> 2) & 1;
    int nb = (bid >> 3) * 4 + (bid & 3);
    if (nb >= 1563) return;
    int n = nb * 32 + (threadIdx.x >> 3);
    if (n >= N_NODES) return;
    int c = (threadIdx.x & 7) * 8;        // col within half
    const unsigned short* XP = XG + (size_t)half * NHALF;

    int e0 = offs[n], e1 = offs[n + 1];
    float a0[8], a1[8];
#pragma unroll
    for (int i = 0; i < 8; ++i) { a0[i] = 0.f; a1[i] = 0.f; }

    int e = e0;
    for (; e + 4 <= e1; e += 4) {
        int s0i = csr[e], s1i = csr[e + 1], s2i = csr[e + 2], s3i = csr[e + 3];
        u16x8 v0 = *reinterpret_cast<const u16x8*>(XP + (size_t)s0i * 64 + c);
        u16x8 v1 = *reinterpret_cast<const u16x8*>(XP + (size_t)s1i * 64 + c);
        u16x8 v2 = *reinterpret_cast<const u16x8*>(XP + (size_t)s2i * 64 + c);
        u16x8 v3 = *reinterpret_cast<const u16x8*>(XP + (size_t)s3i * 64 + c);
#pragma unroll
        for (int i = 0; i < 8; ++i) {
            a0[i] += bff((unsigned short)v0[i]) + bff((unsigned short)v2[i]);
            a1[i] += bff((unsigned short)v1[i]) + bff((unsigned short)v3[i]);
        }
    }
    if (e + 2 <= e1) {
        int s0i = csr[e], s1i = csr[e + 1];
        u16x8 v0 = *reinterpret_cast<const u16x8*>(XP + (size_t)s0i * 64 + c);
        u16x8 v1 = *reinterpret_cast<const u16x8*>(XP + (size_t)s1i * 64 + c);
#pragma unroll
        for (int i = 0; i < 8; ++i) {
            a0[i] += bff((unsigned short)v0[i]);
            a1[i] += bff((unsigned short)v1[i]);
        }
        e += 2;
    }
    if (e < e1) {
        int s0i = csr[e];
        u16x8 v0 = *reinterpret_cast<const u16x8*>(XP + (size_t)s0i * 64 + c);
#pragma unroll
        for (int i = 0; i < 8; ++i)
            a0[i] += bff((unsigned short)v0[i]);
    }
    float id = invdeg[n];
    u16x8 oh, ol;
#pragma unroll
    for (int i = 0; i < 8; ++i) {
        float m = (a0[i] + a1[i]) * id;
        uint32_t h = bfhi(m);
        oh[i] = (unsigned short)h;
        ol[i] = (unsigned short)bfhi(m - bff(h));
    }
    int gc = half * 64 + c;
    int kc = gc >> 5;
    int l = (n & 15) + ((gc >> 3) & 3) * 16;
    size_t unit = ((size_t)(n >> 4) * 4 + kc) * 64 + l;
    *reinterpret_cast<u16x8*>(HNH + unit * 8) = oh;
    *reinterpret_cast<u16x8*>(HNL + unit * 8) = ol;
}

// -------- weight prep (transpose + hi/lo split) + zero degi/sums buffers --------
__global__ __launch_bounds__(256) void k_wprep(const float* __restrict__ W0,
                                               const float* __restrict__ W1,
                                               const float* __restrict__ W2,
                                               const float* __restrict__ W3,
                                               const float* __restrict__ W4,
                                               const float* __restrict__ W5,
                                               unsigned short* __restrict__ wt,
                                               int* __restrict__ degi,
                                               float* __restrict__ sums1,
                                               float* __restrict__ sums2) {
    int gid = blockIdx.x * 256 + threadIdx.x;     // 0..98303
    if (gid < N_NODES) degi[gid] = 0;
    if (gid < 256) { sums1[gid] = 0.f; sums2[gid] = 0.f; }
    int mat = blockIdx.x >> 6;
    const float* srcs[6] = {W0, W1, W2, W3, W4, W5};
    const float* W = srcs[mat];
    int t = (blockIdx.x & 63) * 256 + threadIdx.x;
    int k = t >> 7;
    int n = t & 127;
    float w = W[k * 128 + n];
    uint32_t h = bfhi(w);
    uint32_t l = bfhi(w - bff(h));
    unsigned short* base = wt + (size_t)mat * 32768;
    base[n * 128 + k] = (unsigned short)h;
    base[16384 + n * 128 + k] = (unsigned short)l;
}

// ---------------- MFMA GEMM: fragment-ordered planes, fully coalesced -----------
__global__ __launch_bounds__(256, 4) void k_mm(const unsigned short* __restrict__ PH,
                                               const unsigned short* __restrict__ PL,
                                               const unsigned short* __restrict__ HNH,
                                               const unsigned short* __restrict__ HNL,
                                               const unsigned short* __restrict__ WsT,
                                               const unsigned short* __restrict__ WnT,
                                               const float* __restrict__ bias,
                                               float* __restrict__ OUT,
                                               int doStats,
                                               float* __restrict__ sums) {
    const int tid = threadIdx.x;
    const int lane = tid & 63;
    const int wave = tid >> 6;
    const int mlo = lane & 15;
    const int g = lane >> 4;
    const int ch = blockIdx.x & 1;
    const int t0 = (blockIdx.x >> 1) * 4;
    const int row0 = t0 * 16;
    const int col = ch * 64 + wave * 16 + mlo;
    const float bcol = bias[col];

    f32x4 acc[4];
#pragma unroll
    for (int s = 0; s < 4; ++s) acc[s] = (f32x4){0.f, 0.f, 0.f, 0.f};

#pragma unroll
    for (int kc = 0; kc < 4; ++kc) {
        int ko = kc * 32 + g * 8;
        bf16x8 wsh = *reinterpret_cast<const bf16x8*>(WsT + (size_t)col * 128 + ko);
        bf16x8 wsl = *reinterpret_cast<const bf16x8*>(WsT + 16384 + (size_t)col * 128 + ko);
        bf16x8 wnh = *reinterpret_cast<const bf16x8*>(WnT + (size_t)col * 128 + ko);
        bf16x8 wnl = *reinterpret_cast<const bf16x8*>(WnT + 16384 + (size_t)col * 128 + ko);
#pragma unroll
        for (int s = 0; s < 4; ++s) {
            int t = t0 + s;
            u16x8 xh, xl, ah, al;
            if (t < NT) {
                size_t idx = (((size_t)t * 4 + kc) * 64 + lane) * 8;
                xh = *reinterpret_cast<const u16x8*>(PH + idx);
                xl = *reinterpret_cast<const u16x8*>(PL + idx);
                ah = *reinterpret_cast<const u16x8*>(HNH + idx);
                al = *reinterpret_cast<const u16x8*>(HNL + idx);
            } else {
                u16x8 z = {0, 0, 0, 0, 0, 0, 0, 0};
                xh = z; xl = z; ah = z; al = z;
            }
            bf16x8 bxh = *(bf16x8*)&xh, bxl = *(bf16x8*)&xl;
            bf16x8 bah = *(bf16x8*)&ah, bal = *(bf16x8*)&al;
            acc[s] = __builtin_amdgcn_mfma_f32_16x16x32_bf16(bxh, wsh, acc[s], 0, 0, 0);
            acc[s] = __builtin_amdgcn_mfma_f32_16x16x32_bf16(bxh, wsl, acc[s], 0, 0, 0);
            acc[s] = __builtin_amdgcn_mfma_f32_16x16x32_bf16(bxl, wsh, acc[s], 0, 0, 0);
            acc[s] = __builtin_amdgcn_mfma_f32_16x16x32_bf16(bah, wnh, acc[s], 0, 0, 0);
            acc[s] = __builtin_amdgcn_mfma_f32_16x16x32_bf16(bah, wnl, acc[s], 0, 0, 0);
            acc[s] = __builtin_amdgcn_mfma_f32_16x16x32_bf16(bal, wnh, acc[s], 0, 0, 0);
        }
    }

    // ---- epilogue: bias, store fp32, fused BN stats ----
    float cs = 0.f, cq = 0.f;
#pragma unroll
    for (int s = 0; s < 4; ++s) {
#pragma unroll
        for (int r = 0; r < 4; ++r) {
            int grow = row0 + s * 16 + g * 4 + r;
            if (grow < N_NODES) {
                float v = acc[s][r] + bcol;
                OUT[(size_t)grow * D + col] = v;
                cs += v; cq += v * v;
            }
        }
    }
    if (doStats) {
        cs += __shfl_xor(cs, 16); cs += __shfl_xor(cs, 32);
        cq += __shfl_xor(cq, 16); cq += __shfl_xor(cq, 32);
        if (lane < 16) {
            atomicAdd(&sums[col], cs);
            atomicAdd(&sums[128 + col], cq);
        }
    }
}

// ---------------- launch ----------------
extern "C" void kernel_launch(void* const* d_in, const int* in_sizes, int n_in,
                              void* d_out, int out_size, void* d_ws, size_t ws_size,
                              hipStream_t stream) {
    const float* x   = (const float*)d_in[0];
    const int*   src = (const int*)d_in[1];
    const int*   dst = (const int*)d_in[2];
    const float* Ws1 = (const float*)d_in[3];
    const float* Wn1 = (const float*)d_in[4];
    const float* b1  = (const float*)d_in[5];
    const float* g1  = (const float*)d_in[6];
    const float* be1 = (const float*)d_in[7];
    const float* Ws2 = (const float*)d_in[8];
    const float* Wn2 = (const float*)d_in[9];
    const float* b2  = (const float*)d_in[10];
    const float* g2  = (const float*)d_in[11];
    const float* be2 = (const float*)d_in[12];
    const float* Ws3 = (const float*)d_in[13];
    const float* Wn3 = (const float*)d_in[14];
    const float* b3  = (const float*)d_in[15];
    float* out = (float*)d_out;

    char* p = (char*)d_ws;
    auto alloc = [&](size_t bytes) -> char* {
        char* r = p;
        p += (bytes + 255) & ~(size_t)255;
        return r;
    };
    unsigned short* pfh = (unsigned short*)alloc((size_t)NUNITS * 16);  // fragment hi
    unsigned short* pfl = (unsigned short*)alloc((size_t)NUNITS * 16);  // fragment lo
    unsigned short* xg  = (unsigned short*)alloc((size_t)N_NODES * D * 2); // half-split hi
    unsigned short* hnh = (unsigned short*)alloc((size_t)NUNITS * 16);
    unsigned short* hnl = (unsigned short*)alloc((size_t)NUNITS * 16);
    float* hbuf   = (float*)alloc((size_t)N_NODES * D * 4);
    int*   csr    = (int*)alloc((size_t)NEDGE * 4);
    int*   offs   = (int*)alloc((size_t)(N_NODES + 1) * 4);
    int*   cursor = (int*)alloc((size_t)N_NODES * 4);
    int*   degi   = (int*)alloc((size_t)N_NODES * 4);
    float* invdeg = (float*)alloc((size_t)N_NODES * 4);
    int*   bsum   = (int*)alloc(1024);
    float* sums1  = (float*)alloc(256 * 4);
    float* sums2  = (float*)alloc(256 * 4);
    unsigned short* wt = (unsigned short*)alloc((size_t)6 * 32768 * 2);

    const int NB_N = (N_NODES + 255) / 256;        // 196
    const int NB_A = 3128;                         // 2 halves x 1563 node-blocks
    const int NB_M = 2 * ((N_NODES + 63) / 64);    // 1564
    const int NB_T = (NUNITS + 255) / 256;         // 3125
    const int NB_F = 8 * NB_T;                     // 8 XCD groups x 3125 edge-blocks

    const unsigned short* WsT1 = wt + 0 * 32768;
    const unsigned short* WnT1 = wt + 1 * 32768;
    const unsigned short* WsT2 = wt + 2 * 32768;
    const unsigned short* WnT2 = wt + 3 * 32768;
    const unsigned short* WsT3 = wt + 4 * 32768;
    const unsigned short* WnT3 = wt + 5 * 32768;

    // ---- prep: weights + zero degi/sums, x->planes + deg count, scan, fill ----
    k_wprep<<<384, 256, 0, stream>>>(Ws1, Wn1, Ws2, Wn2, Ws3, Wn3, wt, degi, sums1, sums2);
    k_tobf16<<<NB_T, 256, 0, stream>>>(x, pfh, pfl, xg, dst, degi);
    k_scan1<<<NB_N, 256, 0, stream>>>(degi, offs, bsum);
    k_scan2<<<1, 256, 0, stream>>>(bsum, NB_N);
    k_scan3<<<NB_N, 256, 0, stream>>>(degi, bsum, offs, cursor, invdeg);
    k_fill<<<NB_F, 256, 0, stream>>>(src, dst, cursor, csr);

    // ---- Layer 1 ----
    k_agg<<<NB_A, 256, 0, stream>>>(xg, offs, csr, invdeg, hnh, hnl);
    k_mm<<<NB_M, 256, 0, stream>>>(pfh, pfl, hnh, hnl, WsT1, WnT1, b1, hbuf, 1, sums1);
    k_act<<<NB_T, 256, 0, stream>>>(hbuf, sums1, g1, be1, pfh, pfl, xg);

    // ---- Layer 2 ----
    k_agg<<<NB_A, 256, 0, stream>>>(xg, offs, csr, invdeg, hnh, hnl);
    k_mm<<<NB_M, 256, 0, stream>>>(pfh, pfl, hnh, hnl, WsT2, WnT2, b2, hbuf, 1, sums2);
    k_act<<<NB_T, 256, 0, stream>>>(hbuf, sums2, g2, be2, pfh, pfl, xg);

    // ---- Layer 3 (fp32 out, no stats) ----
    k_agg<<<NB_A, 256, 0, stream>>>(xg, offs, csr, invdeg, hnh, hnl);
    k_mm<<<NB_M, 256, 0, stream>>>(pfh, pfl, hnh, hnl, WsT3, WnT3, b3, out, 0, sums1);
}